// Round 10
// baseline (620.775 us; speedup 1.0000x reference)
//
#include <hip/hip_runtime.h>

#define EPS_BN 1e-5f

constexpr int NN   = 20000;       // nodes
constexpr int NE   = 320000;      // edges
constexpr int NTOT = NE + NN;     // edges + self loops
constexpr int NG   = 512;        // graphs
constexpr int MPAD = 20480;       // 160 * 128 rows
constexpr int NBLK = 79;          // ceil(NN/256)

typedef _Float16 half8  __attribute__((ext_vector_type(8)));
typedef _Float16 half2v __attribute__((ext_vector_type(2)));
typedef float floatx4   __attribute__((ext_vector_type(4)));

// ------------------------------------------------------------------
// Graph preprocessing
// ------------------------------------------------------------------
__global__ void k_deg(const int* __restrict__ col, int* __restrict__ deg,
                      const int* __restrict__ batch, int* __restrict__ gcnt) {
  int e = blockIdx.x * blockDim.x + threadIdx.x;
  if (e >= NTOT) return;
  int c = (e < NE) ? col[e] : (e - NE);
  atomicAdd(&deg[c], 1);
  if (e < NN) atomicAdd(&gcnt[batch[e]], 1);
}

__global__ __launch_bounds__(256) void k_pre1(const int* __restrict__ deg,
                                              float* __restrict__ dinvv,
                                              int* __restrict__ psum) {
  __shared__ int ws[4];
  int t = threadIdx.x, lane = t & 63, wv = t >> 6;
  int idx = blockIdx.x * 256 + t;
  int d = (idx < NN) ? deg[idx] : 0;
  if (idx < NN) dinvv[idx] = rsqrtf((float)d);
  int s = d;
  for (int o = 1; o < 64; o <<= 1) { int u = __shfl_up(s, o, 64); if (lane >= o) s += u; }
  if (lane == 63) ws[wv] = s;
  __syncthreads();
  if (t == 0) psum[blockIdx.x] = ws[0] + ws[1] + ws[2] + ws[3];
}

__global__ __launch_bounds__(256) void k_pre2(const int* __restrict__ psum,
                                              int* __restrict__ pbase,
                                              const int* __restrict__ gcnt,
                                              int* __restrict__ goff) {
  __shared__ int ws[8];
  int t = threadIdx.x, lane = t & 63, wv = t >> 6;
  int v = (t < NBLK) ? psum[t] : 0;
  int inc = v;
  for (int o = 1; o < 64; o <<= 1) { int u = __shfl_up(inc, o, 64); if (lane >= o) inc += u; }
  if (lane == 63) ws[wv] = inc;
  __syncthreads();
  int base = 0;
  for (int w = 0; w < wv; ++w) base += ws[w];
  int excl = base + inc - v;
  if (t < NBLK) pbase[t] = excl;
  if (t == NBLK - 1) pbase[NBLK] = excl + v;
  __syncthreads();
  int a0 = gcnt[2 * t], a1 = gcnt[2 * t + 1];
  int p = a0 + a1;
  int incp = p;
  for (int o = 1; o < 64; o <<= 1) { int u = __shfl_up(incp, o, 64); if (lane >= o) incp += u; }
  if (lane == 63) ws[4 + wv] = incp;
  __syncthreads();
  int gb = 0;
  for (int w = 0; w < wv; ++w) gb += ws[4 + w];
  int exclp = gb + incp - p;
  goff[2 * t]     = exclp;
  goff[2 * t + 1] = exclp + a0;
  if (t == 255) goff[NG] = exclp + p;
}

__global__ __launch_bounds__(256) void k_pre3(const int* __restrict__ deg,
                                              const int* __restrict__ pbase,
                                              int* __restrict__ indptr,
                                              int* __restrict__ cursor) {
  __shared__ int ws[4];
  int t = threadIdx.x, lane = t & 63, wv = t >> 6;
  int idx = blockIdx.x * 256 + t;
  int d = (idx < NN) ? deg[idx] : 0;
  int inc = d;
  for (int o = 1; o < 64; o <<= 1) { int u = __shfl_up(inc, o, 64); if (lane >= o) inc += u; }
  if (lane == 63) ws[wv] = inc;
  __syncthreads();
  int base = pbase[blockIdx.x];
  for (int w = 0; w < wv; ++w) base += ws[w];
  int excl = base + inc - d;
  if (idx < NN) { indptr[idx] = excl; cursor[idx] = excl; }
  if (idx == NN - 1) indptr[NN] = excl + d;
}

__global__ void k_fill(const int* __restrict__ row, const int* __restrict__ col,
                       const float* __restrict__ dinv, int* __restrict__ cursor,
                       int2* __restrict__ csw, float* __restrict__ rsum) {
  int e = blockIdx.x * blockDim.x + threadIdx.x;
  if (e >= NTOT) return;
  int r, c;
  if (e < NE) { r = row[e]; c = col[e]; } else { r = c = e - NE; }
  float wv = dinv[r] * dinv[c];
  int pos = atomicAdd(&cursor[c], 1);
  int2 m; m.x = r; m.y = __builtin_bit_cast(int, wv);
  csw[pos] = m;
  atomicAdd(&rsum[c], wv);
}

// ------------------------------------------------------------------
// MFMA fragment layout: element (n, k) of an [Nrows, K] operand lives at
// ((n>>4)*(K>>5) + (k>>5))*512 + ((k>>3)&3)*128 + (n&15)*8 + (k&7)
// ------------------------------------------------------------------
__device__ __forceinline__ size_t fragoff(int n, int k, int kb) {
  return ((size_t)(n >> 4) * kb + (k >> 5)) * 512 + ((k >> 3) & 3) * 128 + (n & 15) * 8 + (k & 7);
}

// One-shot weight transforms: W1/W4/W5 -> frag fp16; Wf2 -> transposed f32.
__global__ void k_wconv3(const float* __restrict__ W0, const float* __restrict__ W3,
                         const float* __restrict__ W4,
                         _Float16* __restrict__ T0, _Float16* __restrict__ T3,
                         _Float16* __restrict__ T4,
                         const float* __restrict__ Wf2, float* __restrict__ Wf2T) {
  int c = blockIdx.x * blockDim.x + threadIdx.x;   // 16B chunk index
  _Float16 ov[8];
  if (c < 4096) {                                  // W1: N=1024, Kp=32 (K=29)
    int n = c >> 2, k = (c & 3) * 8;
    #pragma unroll
    for (int i = 0; i < 8; ++i)
      ov[i] = (_Float16)((k + i < 29) ? W0[(size_t)(k + i) * 1024 + n] : 0.f);
    *(uint4*)&T0[fragoff(n, k, 1)] = *(const uint4*)ov;
  } else if (c < 4096 + 16384) {                   // W4: N=512, K=256
    int c2 = c - 4096;
    int n = c2 >> 5, k = (c2 & 31) * 8;
    #pragma unroll
    for (int i = 0; i < 8; ++i)
      ov[i] = (_Float16)W3[(size_t)(k + i) * 512 + n];
    *(uint4*)&T3[fragoff(n, k, 8)] = *(const uint4*)ov;
  } else if (c < 4096 + 16384 + 65536) {           // W5: N=1024, K=512
    int c3 = c - 20480;
    int n = c3 >> 6, k = (c3 & 63) * 8;
    #pragma unroll
    for (int i = 0; i < 8; ++i)
      ov[i] = (_Float16)W4[(size_t)(k + i) * 1024 + n];
    *(uint4*)&T4[fragoff(n, k, 16)] = *(const uint4*)ov;
  } else if (c < 86016 + 131072) {                 // Wf2 [1024,128] -> Wf2T [128,1024]
    int idx = c - 86016;
    int o = idx & 127, k = idx >> 7;
    Wf2T[(size_t)o * 1024 + k] = Wf2[idx];
  }
}

// W' = diag(sc) W -> fragment layout fp16; c[n] = sum_k sh_k W[k,n]
__global__ __launch_bounds__(256) void k_wfold(const float* __restrict__ W, int K, int N,
                                               const float* __restrict__ sums,
                                               const float* __restrict__ gamma,
                                               const float* __restrict__ beta,
                                               _Float16* __restrict__ T,
                                               float* __restrict__ c) {
  __shared__ float red[256];
  int n = blockIdx.x, tid = threadIdx.x;
  int kb = K >> 5;
  const float inv_n = 1.f / NN;
  float csum = 0.f;
  for (int kc = tid; kc < (K >> 3); kc += 256) {
    int k = kc * 8;
    _Float16 ov[8];
    #pragma unroll
    for (int i = 0; i < 8; ++i) {
      int ki = k + i;
      float mean = sums[ki] * inv_n;
      float var  = sums[K + ki] * inv_n - mean * mean;
      float sc   = gamma[ki] * rsqrtf(var + EPS_BN);
      float sh   = beta[ki] - mean * sc;
      float wv   = W[(size_t)ki * N + n];
      ov[i] = (_Float16)(sc * wv);
      csum += sh * wv;
    }
    *(uint4*)&T[fragoff(n, k, kb)] = *(const uint4*)ov;
  }
  red[tid] = csum;
  __syncthreads();
  for (int o = 128; o > 0; o >>= 1) {
    if (tid < o) red[tid] += red[tid + o];
    __syncthreads();
  }
  if (tid == 0) c[n] = red[0];
}

// ------------------------------------------------------------------
// L1 aggregation: fp32 x (F=29) -> fp16 FRAGMENT out (Kp=32, kb=1)
// ------------------------------------------------------------------
#define AGG_CH 128
__global__ __launch_bounds__(128) void k_agg29(
    const float* __restrict__ X,
    const int* __restrict__ indptr, const int2* __restrict__ csw,
    _Float16* __restrict__ Y) {
  __shared__ int   s_src[AGG_CH];
  __shared__ float s_w[AGG_CH];
  __shared__ float red[128];
  int node = blockIdx.x;
  int tid  = threadIdx.x;
  int sub  = tid / 29;
  int feat = tid - sub * 29;
  bool act = tid < 116;
  int beg = indptr[node], end = indptr[node + 1];
  float acc = 0.f;
  for (int e0 = beg; e0 < end; e0 += AGG_CH) {
    int c = min(AGG_CH, end - e0);
    if (tid < c) {
      int2 m = csw[e0 + tid];
      s_src[tid] = m.x;
      s_w[tid]   = __builtin_bit_cast(float, m.y);
    }
    __syncthreads();
    if (act) {
      for (int j = 0; j < c; j += 4) {
        int jj = j + sub;
        if (jj < c) acc += s_w[jj] * X[(size_t)s_src[jj] * 29 + feat];
      }
    }
    __syncthreads();
  }
  red[tid] = acc;
  __syncthreads();
  if (tid < 32) {
    float v = 0.f;
    if (tid < 29) v = red[tid] + red[29 + tid] + red[58 + tid] + red[87 + tid];
    size_t fb = (size_t)(node >> 4) * 512 + (size_t)(tid >> 3) * 128 + (node & 15) * 8 + (tid & 7);
    Y[fb] = (_Float16)v;
  }
}

// ------------------------------------------------------------------
// Chunked 4-node-group gather: F/128 chunk-major phases x 128 feats.
// Window per phase = NN*256B = 5.1MB (~one XCD L2). Each 16-lane group
// owns ONE node (16 lanes x 16B = full 128-feat chunk per edge); groups
// with exhausted edge lists are exec-masked (no memory requests), so
// max-of-4 padding costs issue slots only. One epilogue per group, plain
// stores. Economy identical to r8's proven form; window halved again.
// MODE 0: out = relu(acc + s*p0[f] + p1[f])
// MODE 1: out = sc[f]*acc + s*sh[f]  (BN from sums p0, gamma p1, beta p2)
// ------------------------------------------------------------------
template<int F, int MODE>
__global__ __launch_bounds__(256) void k_aggc4(
    const _Float16* __restrict__ X,
    _Float16* __restrict__ Yf, _Float16* __restrict__ Yrow,
    const int* __restrict__ indptr, const int2* __restrict__ csw,
    const float* __restrict__ rowsum,
    const float* __restrict__ p0, const float* __restrict__ p1,
    const float* __restrict__ p2)
{
  constexpr int NB = NN / 16;         // node-blocks per chunk phase
  int bid  = blockIdx.x;
  int c    = bid / NB;                // chunk phase (dispatched in order)
  int nb   = bid - c * NB;
  int wave = threadIdx.x >> 6;
  int lane = threadIdx.x & 63;
  int grp  = lane >> 4;               // 4 nodes per wave, 1 per 16-lane group
  int l16  = lane & 15;
  int node = nb * 16 + wave * 4 + grp;
  int beg  = indptr[node];
  int len  = indptr[node + 1] - beg;
  int len0 = __shfl(len, 0, 64), len1 = __shfl(len, 16, 64);
  int len2 = __shfl(len, 32, 64), len3 = __shfl(len, 48, 64);
  int maxlen = max(max(len0, len1), max(len2, len3));

  float acc[8];
  #pragma unroll
  for (int i = 0; i < 8; ++i) acc[i] = 0.f;
  const unsigned* Xl = (const unsigned*)X + c * 64 + l16 * 4;  // chunk base + sublane

  auto body = [&](int t) {
    if (t < len) {
      int2 m = csw[beg + t];
      float we = __builtin_bit_cast(float, m.y);
      uint4 d = *(const uint4*)(Xl + (size_t)m.x * (F / 2));
      unsigned uu[4] = {d.x, d.y, d.z, d.w};
      #pragma unroll
      for (int i = 0; i < 4; ++i) {
        half2v h = __builtin_bit_cast(half2v, uu[i]);
        acc[2 * i]     = fmaf(we, (float)h[0], acc[2 * i]);
        acc[2 * i + 1] = fmaf(we, (float)h[1], acc[2 * i + 1]);
      }
    }
  };
  int t = 0;
  for (; t + 4 <= maxlen; t += 4) { body(t); body(t + 1); body(t + 2); body(t + 3); }
  for (; t < maxlen; ++t) body(t);

  float s_n = rowsum[node];
  int f0 = c * 128 + l16 * 8;
  _Float16 outv[8];
  #pragma unroll
  for (int i = 0; i < 8; ++i) {
    int f = f0 + i;
    float v;
    if constexpr (MODE == 0) {
      v = fmaxf(acc[i] + s_n * p0[f] + p1[f], 0.f);
    } else {
      const float inv_n = 1.f / NN;
      float mean = p0[f] * inv_n;
      float var  = p0[F + f] * inv_n - mean * mean;
      float sc   = p1[f] * rsqrtf(var + EPS_BN);
      float sh   = p2[f] - mean * sc;
      v = sc * acc[i] + s_n * sh;
    }
    outv[i] = (_Float16)v;
  }
  if (Yf) {
    *(uint4*)&Yf[fragoff(node, f0, F / 32)] = *(const uint4*)outv;
  }
  if (Yrow) {
    *(uint4*)(Yrow + (size_t)node * F + f0) = *(const uint4*)outv;
  }
}

// ------------------------------------------------------------------
// Fragment-layout fp16 MFMA GEMM (streaming; no K-loop LDS / barriers).
// Used for G1 (frag-out, K=32 too small to stage).
// ------------------------------------------------------------------
template<int K, int FRAGOUT>
__global__ __launch_bounds__(256) void k_gemmf(
    const _Float16* __restrict__ Af, const _Float16* __restrict__ Bf,
    const float* __restrict__ bias,
    _Float16* __restrict__ Ch,          // row-major out (FRAGOUT=0)
    _Float16* __restrict__ Cf,          // fragment out  (FRAGOUT=1)
    float* __restrict__ stats,
    int N, int do_relu, int nbx)
{
  __shared__ __align__(16) _Float16 cs[128 * 136];
  __shared__ float sred[256];

  const int tid  = threadIdx.x;
  const int wave = tid >> 6;
  const int lane = tid & 63;

  int lin = blockIdx.x;
  int xcd = lin & 7, seq = lin >> 3;
  int bx = seq % nbx, grp = seq / nbx;
  int by = xcd + 8 * grp;            // 0..159
  const int row0 = by * 128;
  const int col0 = bx * 128;

  const int q  = lane >> 4;
  const int mm = lane & 15;
  const int wm = wave >> 1;
  const int wn = wave & 1;

  sred[tid] = 0.f;

  constexpr int KB = K / 32;
  const _Float16* pa[4];
  const _Float16* pb[4];
  #pragma unroll
  for (int i = 0; i < 4; ++i)
    pa[i] = Af + (size_t)((row0 >> 4) + wm * 4 + i) * (KB * 512) + lane * 8;
  #pragma unroll
  for (int j = 0; j < 4; ++j)
    pb[j] = Bf + (size_t)((col0 >> 4) + wn * 4 + j) * (KB * 512) + lane * 8;

  floatx4 acc[4][4];
  #pragma unroll
  for (int i = 0; i < 4; ++i)
    #pragma unroll
    for (int j = 0; j < 4; ++j) acc[i][j] = floatx4{0.f, 0.f, 0.f, 0.f};

  half8 av[4], bv[4];
  #pragma unroll
  for (int i = 0; i < 4; ++i) { av[i] = *(const half8*)pa[i]; pa[i] += 512; }
  #pragma unroll
  for (int j = 0; j < 4; ++j) { bv[j] = *(const half8*)pb[j]; pb[j] += 512; }

  #pragma unroll 2
  for (int s = 0; s < KB; ++s) {
    half8 nav[4], nbv[4];
    if (s + 1 < KB) {
      #pragma unroll
      for (int i = 0; i < 4; ++i) { nav[i] = *(const half8*)pa[i]; pa[i] += 512; }
      #pragma unroll
      for (int j = 0; j < 4; ++j) { nbv[j] = *(const half8*)pb[j]; pb[j] += 512; }
    }
    #pragma unroll
    for (int j = 0; j < 4; ++j)
      #pragma unroll
      for (int i = 0; i < 4; ++i)
        acc[i][j] = __builtin_amdgcn_mfma_f32_16x16x32_f16(av[i], bv[j], acc[i][j], 0, 0, 0);
    if (s + 1 < KB) {
      #pragma unroll
      for (int i = 0; i < 4; ++i) av[i] = nav[i];
      #pragma unroll
      for (int j = 0; j < 4; ++j) bv[j] = nbv[j];
    }
  }

  __syncthreads();

  float sloc[4]  = {0.f, 0.f, 0.f, 0.f};
  float s2loc[4] = {0.f, 0.f, 0.f, 0.f};
  #pragma unroll
  for (int j = 0; j < 4; ++j) {
    int cl = wn * 64 + j * 16 + mm;
    float bvv = bias ? bias[col0 + cl] : 0.f;
    #pragma unroll
    for (int i = 0; i < 4; ++i) {
      #pragma unroll
      for (int r = 0; r < 4; ++r) {
        int rl = wm * 64 + i * 16 + q * 4 + r;
        float v = acc[i][j][r] + bvv;
        if (do_relu) v = fmaxf(v, 0.f);
        cs[rl * 136 + cl] = (_Float16)v;
        if (row0 + rl < NN) { sloc[j] += v; s2loc[j] += v * v; }
      }
    }
  }

  if (stats) {
    #pragma unroll
    for (int j = 0; j < 4; ++j) {
      float a = sloc[j], b2 = s2loc[j];
      a  += __shfl_xor(a, 16, 64);  a  += __shfl_xor(a, 32, 64);
      b2 += __shfl_xor(b2, 16, 64); b2 += __shfl_xor(b2, 32, 64);
      if (q == 0) {
        int cl = wn * 64 + j * 16 + mm;
        atomicAdd(&sred[cl], a);
        atomicAdd(&sred[128 + cl], b2);
      }
    }
  }
  __syncthreads();

  if (FRAGOUT) {
    int mlo = tid & 15, sub = (tid >> 4) & 3, kcr = (tid >> 6) & 3;
    int kbN = N >> 5;
    #pragma unroll
    for (int pass = 0; pass < 8; ++pass) {
      int m = pass * 16 + mlo;
      int kl = kcr * 32 + sub * 8;
      uint4 d = *(const uint4*)&cs[m * 136 + kl];
      size_t fa = ((size_t)((row0 >> 4) + pass) * kbN + (col0 >> 5) + kcr) * 512
                + sub * 128 + mlo * 8;
      *(uint4*)&Cf[fa] = d;
    }
  } else {
    #pragma unroll
    for (int pass = 0; pass < 8; ++pass) {
      int cidx = tid + pass * 256;
      int r = cidx >> 4, kc = cidx & 15;
      int rr = row0 + r;
      if (rr < NN) {
        uint4 d = *(const uint4*)&cs[r * 136 + kc * 8];
        *(uint4*)&Ch[(size_t)rr * N + col0 + kc * 8] = d;
      }
    }
  }

  if (stats && tid < 128) {
    atomicAdd(&stats[col0 + tid], sred[tid]);
    atomicAdd(&stats[N + col0 + tid], sred[128 + tid]);
  }
}

// ------------------------------------------------------------------
// LDS-staged fp16 MFMA GEMM (m97-style: global_load_lds width-16, BK=64,
// 2 barriers per stage). Proven faster than streaming (round 6, G2/G5).
// Used for all row-major-out GEMMs: G2 (K=1024), G3/G5 (K=512), G4 (K=256).
// ------------------------------------------------------------------
template<int K>
__global__ __launch_bounds__(256) void k_gemmf3(
    const _Float16* __restrict__ Af, const _Float16* __restrict__ Bf,
    const float* __restrict__ bias,
    _Float16* __restrict__ Ch,
    float* __restrict__ stats,
    int N, int do_relu, int nbx)
{
  constexpr int KB = K / 32;          // 32-wide k-blocks per row-group
  constexpr int NS = K / 64;          // staging steps (BK=64)
  // smem: staging A(8192 halfs) + B(8192) = 32KB; epilogue cs 128*136 = 34.8KB
  __shared__ __align__(16) _Float16 smem[128 * 136];
  __shared__ float sred[256];

  const int tid  = threadIdx.x;
  const int wave = tid >> 6;
  const int lane = tid & 63;

  int lin = blockIdx.x;
  int xcd = lin & 7, seq = lin >> 3;
  int bx = seq % nbx, grp = seq / nbx;
  int by = xcd + 8 * grp;            // 0..159
  const int row0 = by * 128;
  const int col0 = bx * 128;

  const int q  = lane >> 4;
  const int mm = lane & 15;
  const int wm = wave >> 1;
  const int wn = wave & 1;

  sred[tid] = 0.f;

  _Float16* ldsA = smem;
  _Float16* ldsB = smem + 8192;

  floatx4 acc[4][4];
  #pragma unroll
  for (int i = 0; i < 4; ++i)
    #pragma unroll
    for (int j = 0; j < 4; ++j) acc[i][j] = floatx4{0.f, 0.f, 0.f, 0.f};

  const int sh  = wave & 1;           // which half of the 2-frag-block pair
  const int frb = wave >> 1;          // base row-group contribution

  for (int s = 0; s < NS; ++s) {
    #pragma unroll
    for (int p = 0; p < 4; ++p) {
      int fr = 2 * p + frb;
      const _Float16* sa = Af + ((size_t)((row0 >> 4) + fr) * KB + 2 * s) * 512
                         + sh * 512 + lane * 8;
      __builtin_amdgcn_global_load_lds(
          (const __attribute__((address_space(1))) void*)sa,
          (__attribute__((address_space(3))) void*)&ldsA[fr * 1024 + sh * 512],
          16, 0, 0);
      const _Float16* sb = Bf + ((size_t)((col0 >> 4) + fr) * KB + 2 * s) * 512
                         + sh * 512 + lane * 8;
      __builtin_amdgcn_global_load_lds(
          (const __attribute__((address_space(1))) void*)sb,
          (__attribute__((address_space(3))) void*)&ldsB[fr * 1024 + sh * 512],
          16, 0, 0);
    }
    __syncthreads();                  // drains vmcnt -> LDS tiles ready
    #pragma unroll
    for (int kk = 0; kk < 2; ++kk) {
      half8 av[4], bv[4];
      #pragma unroll
      for (int i = 0; i < 4; ++i)
        av[i] = *(const half8*)&ldsA[((wm * 4 + i) * 2 + kk) * 512 + lane * 8];
      #pragma unroll
      for (int j = 0; j < 4; ++j)
        bv[j] = *(const half8*)&ldsB[((wn * 4 + j) * 2 + kk) * 512 + lane * 8];
      #pragma unroll
      for (int j = 0; j < 4; ++j)
        #pragma unroll
        for (int i = 0; i < 4; ++i)
          acc[i][j] = __builtin_amdgcn_mfma_f32_16x16x32_f16(av[i], bv[j], acc[i][j], 0, 0, 0);
    }
    __syncthreads();                  // before next stage overwrites LDS
  }

  // ---- epilogue (cs aliases the staging smem; safe after barrier) ----
  _Float16* cs = smem;
  float sloc[4]  = {0.f, 0.f, 0.f, 0.f};
  float s2loc[4] = {0.f, 0.f, 0.f, 0.f};
  #pragma unroll
  for (int j = 0; j < 4; ++j) {
    int cl = wn * 64 + j * 16 + mm;
    float bvv = bias ? bias[col0 + cl] : 0.f;
    #pragma unroll
    for (int i = 0; i < 4; ++i) {
      #pragma unroll
      for (int r = 0; r < 4; ++r) {
        int rl = wm * 64 + i * 16 + q * 4 + r;
        float v = acc[i][j][r] + bvv;
        if (do_relu) v = fmaxf(v, 0.f);
        cs[rl * 136 + cl] = (_Float16)v;
        if (row0 + rl < NN) { sloc[j] += v; s2loc[j] += v * v; }
      }
    }
  }

  if (stats) {
    #pragma unroll
    for (int j = 0; j < 4; ++j) {
      float a = sloc[j], b2 = s2loc[j];
      a  += __shfl_xor(a, 16, 64);  a  += __shfl_xor(a, 32, 64);
      b2 += __shfl_xor(b2, 16, 64); b2 += __shfl_xor(b2, 32, 64);
      if (q == 0) {
        int cl = wn * 64 + j * 16 + mm;
        atomicAdd(&sred[cl], a);
        atomicAdd(&sred[128 + cl], b2);
      }
    }
  }
  __syncthreads();

  #pragma unroll
  for (int pass = 0; pass < 8; ++pass) {
    int cidx = tid + pass * 256;
    int r = cidx >> 4, kc = cidx & 15;
    int rr = row0 + r;
    if (rr < NN) {
      uint4 d = *(const uint4*)&cs[r * 136 + kc * 8];
      *(uint4*)&Ch[(size_t)rr * N + col0 + kc * 8] = d;
    }
  }

  if (stats && tid < 128) {
    atomicAdd(&stats[col0 + tid], sred[tid]);
    atomicAdd(&stats[N + col0 + tid], sred[128 + tid]);
  }
}

// ------------------------------------------------------------------
// BN stats over FRAGMENT-layout fp16 tensor.
// ------------------------------------------------------------------
template<int F>
__global__ __launch_bounds__(256) void k_statsf(const _Float16* __restrict__ Xf,
                                                float* __restrict__ sums) {
  constexpr int KB = F / 32;
  constexpr int NT = NN / 16;
  int wid  = (blockIdx.x * 256 + threadIdx.x) >> 6;
  int lane = threadIdx.x & 63;
  int nw   = (gridDim.x * 256) >> 6;
  int kidx = wid % KB;
  int ng0  = wid / KB;
  int step = nw / KB;
  int sub = lane >> 4, n16 = lane & 15;

  float s[8], s2[8];
  #pragma unroll
  for (int i = 0; i < 8; ++i) { s[i] = 0.f; s2[i] = 0.f; }

  for (int ng = ng0; ng < NT; ng += step) {
    const _Float16* p = Xf + ((size_t)ng * KB + kidx) * 512 + lane * 8;
    uint4 d = *(const uint4*)p;
    unsigned uu[4] = {d.x, d.y, d.z, d.w};
    #pragma unroll
    for (int i = 0; i < 4; ++i) {
      half2v h = __builtin_bit_cast(half2v, uu[i]);
      float v0 = (float)h[0], v1 = (float)h[1];
      s[2 * i]      += v0;  s2[2 * i]     += v0 * v0;
      s[2 * i + 1]  += v1;  s2[2 * i + 1] += v1 * v1;
    }
  }
  #pragma unroll
  for (int o = 1; o < 16; o <<= 1) {
    #pragma unroll
    for (int i = 0; i < 8; ++i) {
      s[i]  += __shfl_xor(s[i],  o, 64);
      s2[i] += __shfl_xor(s2[i], o, 64);
    }
  }
  if (n16 == 0) {
    int f = kidx * 32 + sub * 8;
    #pragma unroll
    for (int i = 0; i < 8; ++i) {
      atomicAdd(&sums[f + i], s[i]);
      atomicAdd(&sums[F + f + i], s2[i]);
    }
  }
}

// ------------------------------------------------------------------
// Slim BN stats over row-major fp16 tensor (stride == F)
// ------------------------------------------------------------------
__global__ __launch_bounds__(256) void k_stats16(const _Float16* __restrict__ X, int F,
                                                 float* __restrict__ sums) {
  int tid = threadIdx.x;
  int npf = F >> 8;
  float s[2] = {0.f, 0.f}, s2[2] = {0.f, 0.f};
  for (int r = blockIdx.x; r < NN; r += gridDim.x) {
    #pragma unroll
    for (int i = 0; i < 2; ++i) {
      if (i < npf) {
        float v = (float)X[(size_t)r * F + tid + i * 256];
        s[i] += v; s2[i] += v * v;
      }
    }
  }
  #pragma unroll
  for (int i = 0; i < 2; ++i) {
    if (i < npf) {
      atomicAdd(&sums[tid + i * 256], s[i]);
      atomicAdd(&sums[F + tid + i * 256], s2[i]);
    }
  }
}

// ------------------------------------------------------------------
// Gate: fold BN5 into gate weights once (1 block), then wave-per-node dot.
// ------------------------------------------------------------------
__global__ __launch_bounds__(256) void k_gfold(const float* __restrict__ sums,
                                               const float* __restrict__ g5,
                                               const float* __restrict__ be5,
                                               const float* __restrict__ Wg,
                                               const float* __restrict__ bg,
                                               float* __restrict__ wgf,
                                               float* __restrict__ cg) {
  __shared__ float red[256];
  int tid = threadIdx.x;
  const float inv_n = 1.f / NN;
  float t = 0.f;
  #pragma unroll
  for (int i = 0; i < 4; ++i) {
    int f = i * 256 + tid;
    float mean = sums[f] * inv_n;
    float var  = sums[1024 + f] * inv_n - mean * mean;
    float sc   = g5[f] * rsqrtf(var + EPS_BN);
    float sh   = be5[f] - mean * sc;
    float wv   = Wg[f];
    wgf[f] = sc * wv;
    t += sh * wv;
  }
  red[tid] = t;
  __syncthreads();
  for (int o = 128; o > 0; o >>= 1) {
    if (tid < o) red[tid] += red[tid + o];
    __syncthreads();
  }
  if (tid == 0) cg[0] = red[0] + bg[0];
}

__global__ __launch_bounds__(256) void k_gate3(const _Float16* __restrict__ X,
                                               const float* __restrict__ wgf,
                                               const float* __restrict__ cg,
                                               float* __restrict__ gate) {
  int wave = threadIdx.x >> 6, lane = threadIdx.x & 63;
  int node = blockIdx.x * 4 + wave;
  const _Float16* xp = X + (size_t)node * 1024 + lane * 16;
  uint4 d0 = *(const uint4*)xp;
  uint4 d1 = *(const uint4*)(xp + 8);
  const float4* wp = (const float4*)(wgf + lane * 16);
  float4 w0 = wp[0], w1 = wp[1], w2 = wp[2], w3 = wp[3];
  float wv[16] = {w0.x, w0.y, w0.z, w0.w, w1.x, w1.y, w1.z, w1.w,
                  w2.x, w2.y, w2.z, w2.w, w3.x, w3.y, w3.z, w3.w};
  unsigned uu[8] = {d0.x, d0.y, d0.z, d0.w, d1.x, d1.y, d1.z, d1.w};
  float s = 0.f;
  #pragma unroll
  for (int i = 0; i < 8; ++i) {
    half2v h = __builtin_bit_cast(half2v, uu[i]);
    s = fmaf((float)h[0], wv[2 * i],     s);
    s = fmaf((float)h[1], wv[2 * i + 1], s);
  }
  #pragma unroll
  for (int o = 1; o < 64; o <<= 1) s += __shfl_xor(s, o, 64);
  if (lane == 0) gate[node] = s + cg[0];
}

// ------------------------------------------------------------------
// Weighted pooling with BN5 fold + inline per-graph softmax.
// ------------------------------------------------------------------
__global__ __launch_bounds__(256) void k_pool(
    const _Float16* __restrict__ X, const float* __restrict__ gate,
    const int* __restrict__ goff,
    const float* __restrict__ sums, const float* __restrict__ g5,
    const float* __restrict__ be5,
    float* __restrict__ pooled)
{
  __shared__ float red[256];
  int g = blockIdx.x >> 2, fc = blockIdx.x & 3;
  int tid = threadIdx.x;
  int f = fc * 256 + tid;
  int beg = goff[g], end = goff[g + 1];

  float m = -3.4e38f;
  for (int n = beg + tid; n < end; n += 256) m = fmaxf(m, gate[n]);
  red[tid] = m;
  __syncthreads();
  for (int o = 128; o > 0; o >>= 1) {
    if (tid < o) red[tid] = fmaxf(red[tid], red[tid + o]);
    __syncthreads();
  }
  m = red[0];
  __syncthreads();
  float s = 0.f;
  for (int n = beg + tid; n < end; n += 256) s += expf(gate[n] - m);
  red[tid] = s;
  __syncthreads();
  for (int o = 128; o > 0; o >>= 1) {
    if (tid < o) red[tid] += red[tid + o];
    __syncthreads();
  }
  float inv = (end > beg) ? (1.f / red[0]) : 0.f;

  const _Float16* Xp = X + f;
  float acc = 0.f;
  int n = beg;
  for (; n + 4 <= end; n += 4) {
    float a0 = expf(gate[n]     - m);
    float a1 = expf(gate[n + 1] - m);
    float a2 = expf(gate[n + 2] - m);
    float a3 = expf(gate[n + 3] - m);
    float x0 = (float)Xp[(size_t)(n)     * 1024];
    float x1 = (float)Xp[(size_t)(n + 1) * 1024];
    float x2 = (float)Xp[(size_t)(n + 2) * 1024];
    float x3 = (float)Xp[(size_t)(n + 3) * 1024];
    acc += a0 * x0 + a1 * x1 + a2 * x2 + a3 * x3;
  }
  for (; n < end; ++n) acc += expf(gate[n] - m) * (float)Xp[(size_t)n * 1024];

  const float inv_n = 1.f / NN;
  float mean = sums[f] * inv_n;
  float var  = sums[1024 + f] * inv_n - mean * mean;
  float sc   = g5[f] * rsqrtf(var + EPS_BN);
  float sh   = be5[f] - mean * sc;
  pooled[(size_t)g * 1024 + f] = (end > beg) ? (acc * inv * sc + sh) : 0.f;
}

// ------------------------------------------------------------------
// MLP head per graph from pooled row (LDS-staged, vectorized Wf2T reads).
// ------------------------------------------------------------------
__global__ __launch_bounds__(256) void k_head(
    const float* __restrict__ pooled,
    const float* __restrict__ Wf2T, const float* __restrict__ bf2,
    const float* __restrict__ Wf3, const float* __restrict__ bf3,
    const float* __restrict__ Wf4, const float* __restrict__ bf4,
    float* __restrict__ out)
{
  __shared__ float sp[1024];
  __shared__ float red[256];
  __shared__ float sp2[128];
  __shared__ float sp3[16];
  int g = blockIdx.x, tid = threadIdx.x;
  *(float4*)&sp[tid * 4] = *(const float4*)&pooled[(size_t)g * 1024 + tid * 4];
  __syncthreads();

  // Linear(1024 -> 128): 2 threads per output, contiguous float4 reads
  {
    int o = tid & 127, hf = tid >> 7;
    const float4* wrow = (const float4*)(Wf2T + (size_t)o * 1024 + hf * 512);
    const float* spp = &sp[hf * 512];
    float s2 = 0.f;
    #pragma unroll 4
    for (int k4 = 0; k4 < 128; ++k4) {
      float4 w = wrow[k4];
      s2 += w.x * spp[k4 * 4] + w.y * spp[k4 * 4 + 1]
          + w.z * spp[k4 * 4 + 2] + w.w * spp[k4 * 4 + 3];
    }
    red[tid] = s2;
  }
  __syncthreads();
  if (tid < 128) sp2[tid] = fmaxf(red[tid] + red[tid + 128] + bf2[tid], 0.f);
  __syncthreads();
  if (tid < 16) {
    float t = bf3[tid];
    for (int k = 0; k < 128; ++k) t += sp2[k] * Wf3[k * 16 + tid];
    sp3[tid] = fmaxf(t, 0.f);
  }
  __syncthreads();
  if (tid == 0) {
    float t = bf4[0];
    for (int k = 0; k < 16; ++k) t += sp3[k] * Wf4[k];
    out[g] = t;
  }
}

// ------------------------------------------------------------------
extern "C" void kernel_launch(void* const* d_in, const int* in_sizes, int n_in,
                              void* d_out, int out_size, void* d_ws, size_t ws_size,
                              hipStream_t stream) {
  const float* x     = (const float*)d_in[0];
  const int*   ei    = (const int*)d_in[1];
  const int*   batch = (const int*)d_in[2];
  const float* W[5]; const float* b[5]; const float* g[5]; const float* be[5];
  for (int l = 0; l < 5; ++l) {
    W[l]  = (const float*)d_in[3 + 4 * l];
    b[l]  = (const float*)d_in[4 + 4 * l];
    g[l]  = (const float*)d_in[5 + 4 * l];
    be[l] = (const float*)d_in[6 + 4 * l];
  }
  const float* Wg  = (const float*)d_in[23];
  const float* bg  = (const float*)d_in[24];
  const float* Wf2 = (const float*)d_in[25];
  const float* bf2 = (const float*)d_in[26];
  const float* Wf3 = (const float*)d_in[27];
  const float* bf3 = (const float*)d_in[28];
  const float* Wf4 = (const float*)d_in[29];
  const float* bf4 = (const float*)d_in[30];
  float* out = (float*)d_out;

  const int* row = ei;
  const int* col = ei + NE;

  char* base = (char*)d_ws;
  size_t off = 0;
  auto alloc = [&](size_t bytes) -> char* {
    char* p = base + off;
    off = (off + bytes + 255) & ~(size_t)255;
    return p;
  };
  // AH: r1(frag,K=1024) -> a4(frag,K=256)
  _Float16*  AH  = (_Float16*)alloc((size_t)MPAD * 1024 * 2);
  // AF: r2(frag,K=512) -> a5(frag,K=512)
  _Float16*  AF  = (_Float16*)alloc((size_t)MPAD * 512 * 2);
  _Float16*  ASM = (_Float16*)alloc((size_t)MPAD * 32 * 2);   // L1 A operand (frag)
  _Float16*  BF  = (_Float16*)alloc((size_t)NN * 512 * 2);    // G2(row) -> r3(row)
  _Float16*  BF2 = (_Float16*)alloc((size_t)NN * 512 * 2);    // G3(row) -> r4(row)
  _Float16*  H5  = (_Float16*)alloc((size_t)NN * 1024 * 2);   // r5(row)
  const int wtsz[5] = {1024 * 32, 512 * 1024, 256 * 512, 512 * 256, 1024 * 512};
  _Float16* WT[5];
  for (int l = 0; l < 5; ++l) WT[l] = (_Float16*)alloc((size_t)wtsz[l] * 2);
  float* c2  = (float*)alloc(512 * 4);
  float* c3  = (float*)alloc(256 * 4);
  float* dinv    = (float*)alloc(NN * 4);
  int*   indptr  = (int*)alloc((NN + 1) * 4);
  int*   cursor  = (int*)alloc(NN * 4);
  int2*  csw     = (int2*)alloc((size_t)NTOT * 8);
  int*   psum    = (int*)alloc((NBLK + 1) * 4);
  int*   pbase   = (int*)alloc((NBLK + 1) * 4);
  int*   goff    = (int*)alloc((NG + 1) * 4);
  float* gate    = (float*)alloc(NN * 4);
  float* wgf     = (float*)alloc(1024 * 4);
  float* cg      = (float*)alloc(4);
  float* pooled  = (float*)alloc((size_t)NG * 1024 * 4);
  float* Wf2T    = (float*)alloc((size_t)128 * 1024 * 4);
  size_t znf = 6656 + NN + NG + NN;
  float* zbase = (float*)alloc(znf * 4);
  float* bns  = zbase;
  int*   deg  = (int*)(zbase + 6656);
  int*   gcnt = (int*)(zbase + 6656 + NN);
  float* rsum = zbase + 6656 + NN + NG;
  float* bns1 = bns;          // F=1024
  float* bns2 = bns + 2048;   // F=512
  float* bns3 = bns + 3072;   // F=256
  float* bns4 = bns + 3584;   // F=512
  float* bns5 = bns + 4608;   // F=1024

  // ---- preprocessing ----
  hipMemsetAsync(zbase, 0, znf * 4, stream);
  k_deg<<<(NTOT + 255) / 256, 256, 0, stream>>>(col, deg, batch, gcnt);
  k_pre1<<<NBLK, 256, 0, stream>>>(deg, dinv, psum);
  k_pre2<<<1, 256, 0, stream>>>(psum, pbase, gcnt, goff);
  k_pre3<<<NBLK, 256, 0, stream>>>(deg, pbase, indptr, cursor);
  k_fill<<<(NTOT + 255) / 256, 256, 0, stream>>>(row, col, dinv, cursor, csw, rsum);
  k_wconv3<<<848, 256, 0, stream>>>(W[0], W[3], W[4], WT[0], WT[3], WT[4], Wf2, Wf2T);

  // ---- layer 1 (29 -> 1024): agg-first (frag); GEMM1 frag-out r1 + stats ----
  k_agg29<<<NN, 128, 0, stream>>>(x, indptr, csw, ASM);
  k_gemmf<32, 1><<<8 * 160, 256, 0, stream>>>(ASM, WT[0], b[0], nullptr, AH, bns1, 1024, 1, 8);

  // ---- layer 2 (1024 -> 512): BN1 folded into W2; transform-first ----
  k_wfold<<<512, 256, 0, stream>>>(W[1], 1024, 512, bns1, g[0], be[0], WT[1], c2);
  k_gemmf3<1024><<<4 * 160, 256, 0, stream>>>(AH, WT[1], nullptr, BF, nullptr, 512, 0, 4); // G2
  k_aggc4<512, 0><<<4 * (NN / 16), 256, 0, stream>>>(BF, AF, nullptr, indptr, csw, rsum, c2, b[1], nullptr); // r2 frag
  k_statsf<512><<<256, 256, 0, stream>>>(AF, bns2);

  // ---- layer 3 (512 -> 256): BN2 folded into W3; transform-first ----
  k_wfold<<<256, 256, 0, stream>>>(W[2], 512, 256, bns2, g[1], be[1], WT[2], c3);
  k_gemmf3<512><<<2 * 160, 256, 0, stream>>>(AF, WT[2], nullptr, BF2, nullptr, 256, 0, 2); // G3
  k_aggc4<256, 0><<<2 * (NN / 16), 256, 0, stream>>>(BF2, nullptr, BF, indptr, csw, rsum, c3, b[2], nullptr); // r3 row
  k_stats16<<<512, 256, 0, stream>>>(BF, 256, bns3);

  // ---- layer 4 (256 -> 512): agg-first (frag), BN3 inline ----
  k_aggc4<256, 1><<<2 * (NN / 16), 256, 0, stream>>>(BF, AH, nullptr, indptr, csw, rsum, bns3, g[2], be[2]); // a4 frag
  k_gemmf3<256><<<4 * 160, 256, 0, stream>>>(AH, WT[3], b[3], BF2, bns4, 512, 1, 4); // r4 + stats

  // ---- layer 5 (512 -> 1024): agg-first (frag), BN4 inline ----
  k_aggc4<512, 1><<<4 * (NN / 16), 256, 0, stream>>>(BF2, AF, nullptr, indptr, csw, rsum, bns4, g[3], be[3]); // a5 frag
  k_gemmf3<512><<<8 * 160, 256, 0, stream>>>(AF, WT[4], b[4], H5, bns5, 1024, 1, 8); // r5 + stats

  // ---- attention pooling (gate -> pool(fused softmax) -> head) ----
  k_gfold<<<1, 256, 0, stream>>>(bns5, g[4], be[4], Wg, bg, wgf, cg);
  k_gate3<<<NN / 4, 256, 0, stream>>>(H5, wgf, cg, gate);
  k_pool<<<NG * 4, 256, 0, stream>>>(H5, gate, goff, bns5, g[4], be[4], pooled);
  k_head<<<NG, 256, 0, stream>>>(pooled, Wf2T, bf2, Wf3, bf3, Wf4, bf4, out);
}

// Round 11
// 558.760 us; speedup vs baseline: 1.1110x; 1.1110x over previous
//
#include <hip/hip_runtime.h>

#define EPS_BN 1e-5f

constexpr int NN   = 20000;       // nodes
constexpr int NE   = 320000;      // edges
constexpr int NTOT = NE + NN;     // edges + self loops
constexpr int NG   = 512;        // graphs
constexpr int MPAD = 20480;       // 160 * 128 rows
constexpr int NBLK = 79;          // ceil(NN/256)

typedef _Float16 half8  __attribute__((ext_vector_type(8)));
typedef _Float16 half2v __attribute__((ext_vector_type(2)));
typedef float floatx4   __attribute__((ext_vector_type(4)));

// ------------------------------------------------------------------
// Graph preprocessing
// ------------------------------------------------------------------
__global__ void k_deg(const int* __restrict__ col, int* __restrict__ deg,
                      const int* __restrict__ batch, int* __restrict__ gcnt) {
  int e = blockIdx.x * blockDim.x + threadIdx.x;
  if (e >= NTOT) return;
  int c = (e < NE) ? col[e] : (e - NE);
  atomicAdd(&deg[c], 1);
  if (e < NN) atomicAdd(&gcnt[batch[e]], 1);
}

__global__ __launch_bounds__(256) void k_pre1(const int* __restrict__ deg,
                                              float* __restrict__ dinvv,
                                              int* __restrict__ psum) {
  __shared__ int ws[4];
  int t = threadIdx.x, lane = t & 63, wv = t >> 6;
  int idx = blockIdx.x * 256 + t;
  int d = (idx < NN) ? deg[idx] : 0;
  if (idx < NN) dinvv[idx] = rsqrtf((float)d);
  int s = d;
  for (int o = 1; o < 64; o <<= 1) { int u = __shfl_up(s, o, 64); if (lane >= o) s += u; }
  if (lane == 63) ws[wv] = s;
  __syncthreads();
  if (t == 0) psum[blockIdx.x] = ws[0] + ws[1] + ws[2] + ws[3];
}

__global__ __launch_bounds__(256) void k_pre2(const int* __restrict__ psum,
                                              int* __restrict__ pbase,
                                              const int* __restrict__ gcnt,
                                              int* __restrict__ goff) {
  __shared__ int ws[8];
  int t = threadIdx.x, lane = t & 63, wv = t >> 6;
  int v = (t < NBLK) ? psum[t] : 0;
  int inc = v;
  for (int o = 1; o < 64; o <<= 1) { int u = __shfl_up(inc, o, 64); if (lane >= o) inc += u; }
  if (lane == 63) ws[wv] = inc;
  __syncthreads();
  int base = 0;
  for (int w = 0; w < wv; ++w) base += ws[w];
  int excl = base + inc - v;
  if (t < NBLK) pbase[t] = excl;
  if (t == NBLK - 1) pbase[NBLK] = excl + v;
  __syncthreads();
  int a0 = gcnt[2 * t], a1 = gcnt[2 * t + 1];
  int p = a0 + a1;
  int incp = p;
  for (int o = 1; o < 64; o <<= 1) { int u = __shfl_up(incp, o, 64); if (lane >= o) incp += u; }
  if (lane == 63) ws[4 + wv] = incp;
  __syncthreads();
  int gb = 0;
  for (int w = 0; w < wv; ++w) gb += ws[4 + w];
  int exclp = gb + incp - p;
  goff[2 * t]     = exclp;
  goff[2 * t + 1] = exclp + a0;
  if (t == 255) goff[NG] = exclp + p;
}

__global__ __launch_bounds__(256) void k_pre3(const int* __restrict__ deg,
                                              const int* __restrict__ pbase,
                                              int* __restrict__ indptr,
                                              int* __restrict__ cursor) {
  __shared__ int ws[4];
  int t = threadIdx.x, lane = t & 63, wv = t >> 6;
  int idx = blockIdx.x * 256 + t;
  int d = (idx < NN) ? deg[idx] : 0;
  int inc = d;
  for (int o = 1; o < 64; o <<= 1) { int u = __shfl_up(inc, o, 64); if (lane >= o) inc += u; }
  if (lane == 63) ws[wv] = inc;
  __syncthreads();
  int base = pbase[blockIdx.x];
  for (int w = 0; w < wv; ++w) base += ws[w];
  int excl = base + inc - d;
  if (idx < NN) { indptr[idx] = excl; cursor[idx] = excl; }
  if (idx == NN - 1) indptr[NN] = excl + d;
}

__global__ void k_fill(const int* __restrict__ row, const int* __restrict__ col,
                       const float* __restrict__ dinv, int* __restrict__ cursor,
                       int2* __restrict__ csw, float* __restrict__ rsum) {
  int e = blockIdx.x * blockDim.x + threadIdx.x;
  if (e >= NTOT) return;
  int r, c;
  if (e < NE) { r = row[e]; c = col[e]; } else { r = c = e - NE; }
  float wv = dinv[r] * dinv[c];
  int pos = atomicAdd(&cursor[c], 1);
  int2 m; m.x = r; m.y = __builtin_bit_cast(int, wv);
  csw[pos] = m;
  atomicAdd(&rsum[c], wv);
}

// ------------------------------------------------------------------
// MFMA fragment layout: element (n, k) of an [Nrows, K] operand lives at
// ((n>>4)*(K>>5) + (k>>5))*512 + ((k>>3)&3)*128 + (n&15)*8 + (k&7)
// ------------------------------------------------------------------
__device__ __forceinline__ size_t fragoff(int n, int k, int kb) {
  return ((size_t)(n >> 4) * kb + (k >> 5)) * 512 + ((k >> 3) & 3) * 128 + (n & 15) * 8 + (k & 7);
}

// One-shot weight transforms: W1/W4/W5 -> frag fp16; Wf2 -> transposed f32.
__global__ void k_wconv3(const float* __restrict__ W0, const float* __restrict__ W3,
                         const float* __restrict__ W4,
                         _Float16* __restrict__ T0, _Float16* __restrict__ T3,
                         _Float16* __restrict__ T4,
                         const float* __restrict__ Wf2, float* __restrict__ Wf2T) {
  int c = blockIdx.x * blockDim.x + threadIdx.x;   // 16B chunk index
  _Float16 ov[8];
  if (c < 4096) {                                  // W1: N=1024, Kp=32 (K=29)
    int n = c >> 2, k = (c & 3) * 8;
    #pragma unroll
    for (int i = 0; i < 8; ++i)
      ov[i] = (_Float16)((k + i < 29) ? W0[(size_t)(k + i) * 1024 + n] : 0.f);
    *(uint4*)&T0[fragoff(n, k, 1)] = *(const uint4*)ov;
  } else if (c < 4096 + 16384) {                   // W4: N=512, K=256
    int c2 = c - 4096;
    int n = c2 >> 5, k = (c2 & 31) * 8;
    #pragma unroll
    for (int i = 0; i < 8; ++i)
      ov[i] = (_Float16)W3[(size_t)(k + i) * 512 + n];
    *(uint4*)&T3[fragoff(n, k, 8)] = *(const uint4*)ov;
  } else if (c < 4096 + 16384 + 65536) {           // W5: N=1024, K=512
    int c3 = c - 20480;
    int n = c3 >> 6, k = (c3 & 63) * 8;
    #pragma unroll
    for (int i = 0; i < 8; ++i)
      ov[i] = (_Float16)W4[(size_t)(k + i) * 1024 + n];
    *(uint4*)&T4[fragoff(n, k, 16)] = *(const uint4*)ov;
  } else if (c < 86016 + 131072) {                 // Wf2 [1024,128] -> Wf2T [128,1024]
    int idx = c - 86016;
    int o = idx & 127, k = idx >> 7;
    Wf2T[(size_t)o * 1024 + k] = Wf2[idx];
  }
}

// W' = diag(sc) W -> fragment layout fp16; c[n] = sum_k sh_k W[k,n]
__global__ __launch_bounds__(256) void k_wfold(const float* __restrict__ W, int K, int N,
                                               const float* __restrict__ sums,
                                               const float* __restrict__ gamma,
                                               const float* __restrict__ beta,
                                               _Float16* __restrict__ T,
                                               float* __restrict__ c) {
  __shared__ float red[256];
  int n = blockIdx.x, tid = threadIdx.x;
  int kb = K >> 5;
  const float inv_n = 1.f / NN;
  float csum = 0.f;
  for (int kc = tid; kc < (K >> 3); kc += 256) {
    int k = kc * 8;
    _Float16 ov[8];
    #pragma unroll
    for (int i = 0; i < 8; ++i) {
      int ki = k + i;
      float mean = sums[ki] * inv_n;
      float var  = sums[K + ki] * inv_n - mean * mean;
      float sc   = gamma[ki] * rsqrtf(var + EPS_BN);
      float sh   = beta[ki] - mean * sc;
      float wv   = W[(size_t)ki * N + n];
      ov[i] = (_Float16)(sc * wv);
      csum += sh * wv;
    }
    *(uint4*)&T[fragoff(n, k, kb)] = *(const uint4*)ov;
  }
  red[tid] = csum;
  __syncthreads();
  for (int o = 128; o > 0; o >>= 1) {
    if (tid < o) red[tid] += red[tid + o];
    __syncthreads();
  }
  if (tid == 0) c[n] = red[0];
}

// ------------------------------------------------------------------
// L1 aggregation: fp32 x (F=29) -> fp16 FRAGMENT out (Kp=32, kb=1)
// ------------------------------------------------------------------
#define AGG_CH 128
__global__ __launch_bounds__(128) void k_agg29(
    const float* __restrict__ X,
    const int* __restrict__ indptr, const int2* __restrict__ csw,
    _Float16* __restrict__ Y) {
  __shared__ int   s_src[AGG_CH];
  __shared__ float s_w[AGG_CH];
  __shared__ float red[128];
  int node = blockIdx.x;
  int tid  = threadIdx.x;
  int sub  = tid / 29;
  int feat = tid - sub * 29;
  bool act = tid < 116;
  int beg = indptr[node], end = indptr[node + 1];
  float acc = 0.f;
  for (int e0 = beg; e0 < end; e0 += AGG_CH) {
    int c = min(AGG_CH, end - e0);
    if (tid < c) {
      int2 m = csw[e0 + tid];
      s_src[tid] = m.x;
      s_w[tid]   = __builtin_bit_cast(float, m.y);
    }
    __syncthreads();
    if (act) {
      for (int j = 0; j < c; j += 4) {
        int jj = j + sub;
        if (jj < c) acc += s_w[jj] * X[(size_t)s_src[jj] * 29 + feat];
      }
    }
    __syncthreads();
  }
  red[tid] = acc;
  __syncthreads();
  if (tid < 32) {
    float v = 0.f;
    if (tid < 29) v = red[tid] + red[29 + tid] + red[58 + tid] + red[87 + tid];
    size_t fb = (size_t)(node >> 4) * 512 + (size_t)(tid >> 3) * 128 + (node & 15) * 8 + (tid & 7);
    Y[fb] = (_Float16)v;
  }
}

// ------------------------------------------------------------------
// F=512 chunked paired-node gather: 2 chunk-major phases x 256 feats.
// PROVEN OPTIMUM (r8: 45us, FETCH 125MB). r10's further halving to 128-feat
// chunks regressed (61us): window already L2-resident at 10.2MB; 16-lane
// groups halve bytes/VMEM-issue. Keep: 2 nodes/wave, 32-lane 16B loads.
// MODE 0: out = relu(acc + s*p0[f] + p1[f])
// MODE 1: out = sc[f]*acc + s*sh[f]  (BN from sums p0, gamma p1, beta p2)
// ------------------------------------------------------------------
template<int MODE>
__global__ __launch_bounds__(256) void k_aggv2(
    const _Float16* __restrict__ X,
    _Float16* __restrict__ Yf, _Float16* __restrict__ Yrow,
    const int* __restrict__ indptr, const int2* __restrict__ csw,
    const float* __restrict__ rowsum,
    const float* __restrict__ p0, const float* __restrict__ p1,
    const float* __restrict__ p2)
{
  constexpr int F = 512;
  constexpr int NB = NN / 8;          // node-blocks per chunk phase
  int bid  = blockIdx.x;
  int c    = bid / NB;                // chunk phase 0/1 (dispatched in order)
  int nb   = bid - c * NB;
  int wave = threadIdx.x >> 6;
  int lane = threadIdx.x & 63;
  int half = lane >> 5;
  int l32  = lane & 31;
  int node = nb * 8 + wave * 2 + half;
  int beg = indptr[node], end = indptr[node + 1];
  int len = end - beg;
  int len0 = __shfl(len, 0, 64);
  int len1 = __shfl(len, 32, 64);
  int maxlen = max(len0, len1);

  float acc[8];
  #pragma unroll
  for (int i = 0; i < 8; ++i) acc[i] = 0.f;
  const unsigned* Xl = (const unsigned*)X + c * 128 + l32 * 4;

  auto body = [&](int t) {
    int e = beg + min(t, len - 1);    // len >= 1 (self loop)
    int2 m = csw[e];
    float we = (t < len) ? __builtin_bit_cast(float, m.y) : 0.f;
    uint4 d = *(const uint4*)(Xl + (size_t)m.x * (F / 2));
    unsigned uu[4] = {d.x, d.y, d.z, d.w};
    #pragma unroll
    for (int i = 0; i < 4; ++i) {
      half2v h = __builtin_bit_cast(half2v, uu[i]);
      acc[2 * i]     = fmaf(we, (float)h[0], acc[2 * i]);
      acc[2 * i + 1] = fmaf(we, (float)h[1], acc[2 * i + 1]);
    }
  };
  int t = 0;
  for (; t + 4 <= maxlen; t += 4) { body(t); body(t + 1); body(t + 2); body(t + 3); }
  for (; t < maxlen; ++t) body(t);

  float s_n = rowsum[node];
  int f0 = c * 256 + l32 * 8;
  _Float16 outv[8];
  #pragma unroll
  for (int i = 0; i < 8; ++i) {
    int f = f0 + i;
    float v;
    if constexpr (MODE == 0) {
      v = fmaxf(acc[i] + s_n * p0[f] + p1[f], 0.f);
    } else {
      const float inv_n = 1.f / NN;
      float mean = p0[f] * inv_n;
      float var  = p0[F + f] * inv_n - mean * mean;
      float sc   = p1[f] * rsqrtf(var + EPS_BN);
      float sh   = p2[f] - mean * sc;
      v = sc * acc[i] + s_n * sh;
    }
    outv[i] = (_Float16)v;
  }
  if (Yf) {
    *(uint4*)&Yf[fragoff(node, f0, 16)] = *(const uint4*)outv;
  }
  if (Yrow) {
    *(uint4*)(Yrow + (size_t)node * F + f0) = *(const uint4*)outv;
  }
}

// ------------------------------------------------------------------
// Paired-node fp16 gather aggregation F=256 (2 nodes/wave, 16B loads).
// ------------------------------------------------------------------
template<int MODE>
__global__ __launch_bounds__(256) void k_aggp(
    const _Float16* __restrict__ X,
    _Float16* __restrict__ Yf, _Float16* __restrict__ Yrow,
    const int* __restrict__ indptr, const int2* __restrict__ csw,
    const float* __restrict__ rowsum,
    const float* __restrict__ p0, const float* __restrict__ p1,
    const float* __restrict__ p2)
{
  constexpr int F = 256;
  int wave = threadIdx.x >> 6;
  int lane = threadIdx.x & 63;
  int half = lane >> 5;
  int l32  = lane & 31;
  int node = blockIdx.x * 8 + wave * 2 + half;
  int beg = indptr[node], end = indptr[node + 1];
  int len = end - beg;
  int len0 = __shfl(len, 0, 64);
  int len1 = __shfl(len, 32, 64);
  int maxlen = max(len0, len1);

  float acc[8];
  #pragma unroll
  for (int i = 0; i < 8; ++i) acc[i] = 0.f;
  const unsigned* Xl = (const unsigned*)X + l32 * 4;

  auto body = [&](int t) {
    int e = beg + min(t, len - 1);
    int2 m = csw[e];
    float we = (t < len) ? __builtin_bit_cast(float, m.y) : 0.f;
    uint4 d = *(const uint4*)(Xl + (size_t)m.x * (F / 2));
    unsigned uu[4] = {d.x, d.y, d.z, d.w};
    #pragma unroll
    for (int i = 0; i < 4; ++i) {
      half2v h = __builtin_bit_cast(half2v, uu[i]);
      acc[2 * i]     = fmaf(we, (float)h[0], acc[2 * i]);
      acc[2 * i + 1] = fmaf(we, (float)h[1], acc[2 * i + 1]);
    }
  };
  int t = 0;
  for (; t + 4 <= maxlen; t += 4) { body(t); body(t + 1); body(t + 2); body(t + 3); }
  for (; t < maxlen; ++t) body(t);

  float s_n = rowsum[node];
  _Float16 outv[8];
  #pragma unroll
  for (int i = 0; i < 8; ++i) {
    int f = l32 * 8 + i;
    float v;
    if constexpr (MODE == 0) {
      v = fmaxf(acc[i] + s_n * p0[f] + p1[f], 0.f);
    } else {
      const float inv_n = 1.f / NN;
      float mean = p0[f] * inv_n;
      float var  = p0[F + f] * inv_n - mean * mean;
      float sc   = p1[f] * rsqrtf(var + EPS_BN);
      float sh   = p2[f] - mean * sc;
      v = sc * acc[i] + s_n * sh;
    }
    outv[i] = (_Float16)v;
  }
  if (Yf) {
    size_t fb = (size_t)(node >> 4) * (8 * 512) + l32 * 128 + (node & 15) * 8;
    *(uint4*)(Yf + fb) = *(const uint4*)outv;
  }
  if (Yrow) {
    *(uint4*)(Yrow + (size_t)node * F + l32 * 8) = *(const uint4*)outv;
  }
}

// ------------------------------------------------------------------
// Fragment-layout fp16 MFMA GEMM (streaming; no K-loop LDS / barriers).
// Used for G1 (frag-out, K=32 too small to stage).
// ------------------------------------------------------------------
template<int K, int FRAGOUT>
__global__ __launch_bounds__(256) void k_gemmf(
    const _Float16* __restrict__ Af, const _Float16* __restrict__ Bf,
    const float* __restrict__ bias,
    _Float16* __restrict__ Ch,          // row-major out (FRAGOUT=0)
    _Float16* __restrict__ Cf,          // fragment out  (FRAGOUT=1)
    float* __restrict__ stats,
    int N, int do_relu, int nbx)
{
  __shared__ __align__(16) _Float16 cs[128 * 136];
  __shared__ float sred[256];

  const int tid  = threadIdx.x;
  const int wave = tid >> 6;
  const int lane = tid & 63;

  int lin = blockIdx.x;
  int xcd = lin & 7, seq = lin >> 3;
  int bx = seq % nbx, grp = seq / nbx;
  int by = xcd + 8 * grp;            // 0..159
  const int row0 = by * 128;
  const int col0 = bx * 128;

  const int q  = lane >> 4;
  const int mm = lane & 15;
  const int wm = wave >> 1;
  const int wn = wave & 1;

  sred[tid] = 0.f;

  constexpr int KB = K / 32;
  const _Float16* pa[4];
  const _Float16* pb[4];
  #pragma unroll
  for (int i = 0; i < 4; ++i)
    pa[i] = Af + (size_t)((row0 >> 4) + wm * 4 + i) * (KB * 512) + lane * 8;
  #pragma unroll
  for (int j = 0; j < 4; ++j)
    pb[j] = Bf + (size_t)((col0 >> 4) + wn * 4 + j) * (KB * 512) + lane * 8;

  floatx4 acc[4][4];
  #pragma unroll
  for (int i = 0; i < 4; ++i)
    #pragma unroll
    for (int j = 0; j < 4; ++j) acc[i][j] = floatx4{0.f, 0.f, 0.f, 0.f};

  half8 av[4], bv[4];
  #pragma unroll
  for (int i = 0; i < 4; ++i) { av[i] = *(const half8*)pa[i]; pa[i] += 512; }
  #pragma unroll
  for (int j = 0; j < 4; ++j) { bv[j] = *(const half8*)pb[j]; pb[j] += 512; }

  #pragma unroll 2
  for (int s = 0; s < KB; ++s) {
    half8 nav[4], nbv[4];
    if (s + 1 < KB) {
      #pragma unroll
      for (int i = 0; i < 4; ++i) { nav[i] = *(const half8*)pa[i]; pa[i] += 512; }
      #pragma unroll
      for (int j = 0; j < 4; ++j) { nbv[j] = *(const half8*)pb[j]; pb[j] += 512; }
    }
    #pragma unroll
    for (int j = 0; j < 4; ++j)
      #pragma unroll
      for (int i = 0; i < 4; ++i)
        acc[i][j] = __builtin_amdgcn_mfma_f32_16x16x32_f16(av[i], bv[j], acc[i][j], 0, 0, 0);
    if (s + 1 < KB) {
      #pragma unroll
      for (int i = 0; i < 4; ++i) av[i] = nav[i];
      #pragma unroll
      for (int j = 0; j < 4; ++j) bv[j] = nbv[j];
    }
  }

  __syncthreads();

  float sloc[4]  = {0.f, 0.f, 0.f, 0.f};
  float s2loc[4] = {0.f, 0.f, 0.f, 0.f};
  #pragma unroll
  for (int j = 0; j < 4; ++j) {
    int cl = wn * 64 + j * 16 + mm;
    float bvv = bias ? bias[col0 + cl] : 0.f;
    #pragma unroll
    for (int i = 0; i < 4; ++i) {
      #pragma unroll
      for (int r = 0; r < 4; ++r) {
        int rl = wm * 64 + i * 16 + q * 4 + r;
        float v = acc[i][j][r] + bvv;
        if (do_relu) v = fmaxf(v, 0.f);
        cs[rl * 136 + cl] = (_Float16)v;
        if (row0 + rl < NN) { sloc[j] += v; s2loc[j] += v * v; }
      }
    }
  }

  if (stats) {
    #pragma unroll
    for (int j = 0; j < 4; ++j) {
      float a = sloc[j], b2 = s2loc[j];
      a  += __shfl_xor(a, 16, 64);  a  += __shfl_xor(a, 32, 64);
      b2 += __shfl_xor(b2, 16, 64); b2 += __shfl_xor(b2, 32, 64);
      if (q == 0) {
        int cl = wn * 64 + j * 16 + mm;
        atomicAdd(&sred[cl], a);
        atomicAdd(&sred[128 + cl], b2);
      }
    }
  }
  __syncthreads();

  if (FRAGOUT) {
    int mlo = tid & 15, sub = (tid >> 4) & 3, kcr = (tid >> 6) & 3;
    int kbN = N >> 5;
    #pragma unroll
    for (int pass = 0; pass < 8; ++pass) {
      int m = pass * 16 + mlo;
      int kl = kcr * 32 + sub * 8;
      uint4 d = *(const uint4*)&cs[m * 136 + kl];
      size_t fa = ((size_t)((row0 >> 4) + pass) * kbN + (col0 >> 5) + kcr) * 512
                + sub * 128 + mlo * 8;
      *(uint4*)&Cf[fa] = d;
    }
  } else {
    #pragma unroll
    for (int pass = 0; pass < 8; ++pass) {
      int cidx = tid + pass * 256;
      int r = cidx >> 4, kc = cidx & 15;
      int rr = row0 + r;
      if (rr < NN) {
        uint4 d = *(const uint4*)&cs[r * 136 + kc * 8];
        *(uint4*)&Ch[(size_t)rr * N + col0 + kc * 8] = d;
      }
    }
  }

  if (stats && tid < 128) {
    atomicAdd(&stats[col0 + tid], sred[tid]);
    atomicAdd(&stats[N + col0 + tid], sred[128 + tid]);
  }
}

// ------------------------------------------------------------------
// LDS-staged fp16 MFMA GEMM (m97-style: global_load_lds width-16, BK=64,
// 2 barriers per stage). Proven faster than streaming (round 6, G2/G5).
// Used for all row-major-out GEMMs: G2 (K=1024), G3/G5 (K=512), G4 (K=256).
// ------------------------------------------------------------------
template<int K>
__global__ __launch_bounds__(256) void k_gemmf3(
    const _Float16* __restrict__ Af, const _Float16* __restrict__ Bf,
    const float* __restrict__ bias,
    _Float16* __restrict__ Ch,
    float* __restrict__ stats,
    int N, int do_relu, int nbx)
{
  constexpr int KB = K / 32;          // 32-wide k-blocks per row-group
  constexpr int NS = K / 64;          // staging steps (BK=64)
  // smem: staging A(8192 halfs) + B(8192) = 32KB; epilogue cs 128*136 = 34.8KB
  __shared__ __align__(16) _Float16 smem[128 * 136];
  __shared__ float sred[256];

  const int tid  = threadIdx.x;
  const int wave = tid >> 6;
  const int lane = tid & 63;

  int lin = blockIdx.x;
  int xcd = lin & 7, seq = lin >> 3;
  int bx = seq % nbx, grp = seq / nbx;
  int by = xcd + 8 * grp;            // 0..159
  const int row0 = by * 128;
  const int col0 = bx * 128;

  const int q  = lane >> 4;
  const int mm = lane & 15;
  const int wm = wave >> 1;
  const int wn = wave & 1;

  sred[tid] = 0.f;

  _Float16* ldsA = smem;
  _Float16* ldsB = smem + 8192;

  floatx4 acc[4][4];
  #pragma unroll
  for (int i = 0; i < 4; ++i)
    #pragma unroll
    for (int j = 0; j < 4; ++j) acc[i][j] = floatx4{0.f, 0.f, 0.f, 0.f};

  const int sh  = wave & 1;           // which half of the 2-frag-block pair
  const int frb = wave >> 1;          // base row-group contribution

  for (int s = 0; s < NS; ++s) {
    #pragma unroll
    for (int p = 0; p < 4; ++p) {
      int fr = 2 * p + frb;
      const _Float16* sa = Af + ((size_t)((row0 >> 4) + fr) * KB + 2 * s) * 512
                         + sh * 512 + lane * 8;
      __builtin_amdgcn_global_load_lds(
          (const __attribute__((address_space(1))) void*)sa,
          (__attribute__((address_space(3))) void*)&ldsA[fr * 1024 + sh * 512],
          16, 0, 0);
      const _Float16* sb = Bf + ((size_t)((col0 >> 4) + fr) * KB + 2 * s) * 512
                         + sh * 512 + lane * 8;
      __builtin_amdgcn_global_load_lds(
          (const __attribute__((address_space(1))) void*)sb,
          (__attribute__((address_space(3))) void*)&ldsB[fr * 1024 + sh * 512],
          16, 0, 0);
    }
    __syncthreads();                  // drains vmcnt -> LDS tiles ready
    #pragma unroll
    for (int kk = 0; kk < 2; ++kk) {
      half8 av[4], bv[4];
      #pragma unroll
      for (int i = 0; i < 4; ++i)
        av[i] = *(const half8*)&ldsA[((wm * 4 + i) * 2 + kk) * 512 + lane * 8];
      #pragma unroll
      for (int j = 0; j < 4; ++j)
        bv[j] = *(const half8*)&ldsB[((wn * 4 + j) * 2 + kk) * 512 + lane * 8];
      #pragma unroll
      for (int j = 0; j < 4; ++j)
        #pragma unroll
        for (int i = 0; i < 4; ++i)
          acc[i][j] = __builtin_amdgcn_mfma_f32_16x16x32_f16(av[i], bv[j], acc[i][j], 0, 0, 0);
    }
    __syncthreads();                  // before next stage overwrites LDS
  }

  // ---- epilogue (cs aliases the staging smem; safe after barrier) ----
  _Float16* cs = smem;
  float sloc[4]  = {0.f, 0.f, 0.f, 0.f};
  float s2loc[4] = {0.f, 0.f, 0.f, 0.f};
  #pragma unroll
  for (int j = 0; j < 4; ++j) {
    int cl = wn * 64 + j * 16 + mm;
    float bvv = bias ? bias[col0 + cl] : 0.f;
    #pragma unroll
    for (int i = 0; i < 4; ++i) {
      #pragma unroll
      for (int r = 0; r < 4; ++r) {
        int rl = wm * 64 + i * 16 + q * 4 + r;
        float v = acc[i][j][r] + bvv;
        if (do_relu) v = fmaxf(v, 0.f);
        cs[rl * 136 + cl] = (_Float16)v;
        if (row0 + rl < NN) { sloc[j] += v; s2loc[j] += v * v; }
      }
    }
  }

  if (stats) {
    #pragma unroll
    for (int j = 0; j < 4; ++j) {
      float a = sloc[j], b2 = s2loc[j];
      a  += __shfl_xor(a, 16, 64);  a  += __shfl_xor(a, 32, 64);
      b2 += __shfl_xor(b2, 16, 64); b2 += __shfl_xor(b2, 32, 64);
      if (q == 0) {
        int cl = wn * 64 + j * 16 + mm;
        atomicAdd(&sred[cl], a);
        atomicAdd(&sred[128 + cl], b2);
      }
    }
  }
  __syncthreads();

  #pragma unroll
  for (int pass = 0; pass < 8; ++pass) {
    int cidx = tid + pass * 256;
    int r = cidx >> 4, kc = cidx & 15;
    int rr = row0 + r;
    if (rr < NN) {
      uint4 d = *(const uint4*)&cs[r * 136 + kc * 8];
      *(uint4*)&Ch[(size_t)rr * N + col0 + kc * 8] = d;
    }
  }

  if (stats && tid < 128) {
    atomicAdd(&stats[col0 + tid], sred[tid]);
    atomicAdd(&stats[N + col0 + tid], sred[128 + tid]);
  }
}

// ------------------------------------------------------------------
// BN stats over FRAGMENT-layout fp16 tensor.
// ------------------------------------------------------------------
template<int F>
__global__ __launch_bounds__(256) void k_statsf(const _Float16* __restrict__ Xf,
                                                float* __restrict__ sums) {
  constexpr int KB = F / 32;
  constexpr int NT = NN / 16;
  int wid  = (blockIdx.x * 256 + threadIdx.x) >> 6;
  int lane = threadIdx.x & 63;
  int nw   = (gridDim.x * 256) >> 6;
  int kidx = wid % KB;
  int ng0  = wid / KB;
  int step = nw / KB;
  int sub = lane >> 4, n16 = lane & 15;

  float s[8], s2[8];
  #pragma unroll
  for (int i = 0; i < 8; ++i) { s[i] = 0.f; s2[i] = 0.f; }

  for (int ng = ng0; ng < NT; ng += step) {
    const _Float16* p = Xf + ((size_t)ng * KB + kidx) * 512 + lane * 8;
    uint4 d = *(const uint4*)p;
    unsigned uu[4] = {d.x, d.y, d.z, d.w};
    #pragma unroll
    for (int i = 0; i < 4; ++i) {
      half2v h = __builtin_bit_cast(half2v, uu[i]);
      float v0 = (float)h[0], v1 = (float)h[1];
      s[2 * i]      += v0;  s2[2 * i]     += v0 * v0;
      s[2 * i + 1]  += v1;  s2[2 * i + 1] += v1 * v1;
    }
  }
  #pragma unroll
  for (int o = 1; o < 16; o <<= 1) {
    #pragma unroll
    for (int i = 0; i < 8; ++i) {
      s[i]  += __shfl_xor(s[i],  o, 64);
      s2[i] += __shfl_xor(s2[i], o, 64);
    }
  }
  if (n16 == 0) {
    int f = kidx * 32 + sub * 8;
    #pragma unroll
    for (int i = 0; i < 8; ++i) {
      atomicAdd(&sums[f + i], s[i]);
      atomicAdd(&sums[F + f + i], s2[i]);
    }
  }
}

// ------------------------------------------------------------------
// Slim BN stats over row-major fp16 tensor (stride == F)
// ------------------------------------------------------------------
__global__ __launch_bounds__(256) void k_stats16(const _Float16* __restrict__ X, int F,
                                                 float* __restrict__ sums) {
  int tid = threadIdx.x;
  int npf = F >> 8;
  float s[2] = {0.f, 0.f}, s2[2] = {0.f, 0.f};
  for (int r = blockIdx.x; r < NN; r += gridDim.x) {
    #pragma unroll
    for (int i = 0; i < 2; ++i) {
      if (i < npf) {
        float v = (float)X[(size_t)r * F + tid + i * 256];
        s[i] += v; s2[i] += v * v;
      }
    }
  }
  #pragma unroll
  for (int i = 0; i < 2; ++i) {
    if (i < npf) {
      atomicAdd(&sums[tid + i * 256], s[i]);
      atomicAdd(&sums[F + tid + i * 256], s2[i]);
    }
  }
}

// ------------------------------------------------------------------
// Gate: fold BN5 into gate weights once (1 block), then wave-per-node dot.
// ------------------------------------------------------------------
__global__ __launch_bounds__(256) void k_gfold(const float* __restrict__ sums,
                                               const float* __restrict__ g5,
                                               const float* __restrict__ be5,
                                               const float* __restrict__ Wg,
                                               const float* __restrict__ bg,
                                               float* __restrict__ wgf,
                                               float* __restrict__ cg) {
  __shared__ float red[256];
  int tid = threadIdx.x;
  const float inv_n = 1.f / NN;
  float t = 0.f;
  #pragma unroll
  for (int i = 0; i < 4; ++i) {
    int f = i * 256 + tid;
    float mean = sums[f] * inv_n;
    float var  = sums[1024 + f] * inv_n - mean * mean;
    float sc   = g5[f] * rsqrtf(var + EPS_BN);
    float sh   = be5[f] - mean * sc;
    float wv   = Wg[f];
    wgf[f] = sc * wv;
    t += sh * wv;
  }
  red[tid] = t;
  __syncthreads();
  for (int o = 128; o > 0; o >>= 1) {
    if (tid < o) red[tid] += red[tid + o];
    __syncthreads();
  }
  if (tid == 0) cg[0] = red[0] + bg[0];
}

__global__ __launch_bounds__(256) void k_gate3(const _Float16* __restrict__ X,
                                               const float* __restrict__ wgf,
                                               const float* __restrict__ cg,
                                               float* __restrict__ gate) {
  int wave = threadIdx.x >> 6, lane = threadIdx.x & 63;
  int node = blockIdx.x * 4 + wave;
  const _Float16* xp = X + (size_t)node * 1024 + lane * 16;
  uint4 d0 = *(const uint4*)xp;
  uint4 d1 = *(const uint4*)(xp + 8);
  const float4* wp = (const float4*)(wgf + lane * 16);
  float4 w0 = wp[0], w1 = wp[1], w2 = wp[2], w3 = wp[3];
  float wv[16] = {w0.x, w0.y, w0.z, w0.w, w1.x, w1.y, w1.z, w1.w,
                  w2.x, w2.y, w2.z, w2.w, w3.x, w3.y, w3.z, w3.w};
  unsigned uu[8] = {d0.x, d0.y, d0.z, d0.w, d1.x, d1.y, d1.z, d1.w};
  float s = 0.f;
  #pragma unroll
  for (int i = 0; i < 8; ++i) {
    half2v h = __builtin_bit_cast(half2v, uu[i]);
    s = fmaf((float)h[0], wv[2 * i],     s);
    s = fmaf((float)h[1], wv[2 * i + 1], s);
  }
  #pragma unroll
  for (int o = 1; o < 64; o <<= 1) s += __shfl_xor(s, o, 64);
  if (lane == 0) gate[node] = s + cg[0];
}

// ------------------------------------------------------------------
// Weighted pooling with BN5 fold + inline per-graph softmax.
// ------------------------------------------------------------------
__global__ __launch_bounds__(256) void k_pool(
    const _Float16* __restrict__ X, const float* __restrict__ gate,
    const int* __restrict__ goff,
    const float* __restrict__ sums, const float* __restrict__ g5,
    const float* __restrict__ be5,
    float* __restrict__ pooled)
{
  __shared__ float red[256];
  int g = blockIdx.x >> 2, fc = blockIdx.x & 3;
  int tid = threadIdx.x;
  int f = fc * 256 + tid;
  int beg = goff[g], end = goff[g + 1];

  float m = -3.4e38f;
  for (int n = beg + tid; n < end; n += 256) m = fmaxf(m, gate[n]);
  red[tid] = m;
  __syncthreads();
  for (int o = 128; o > 0; o >>= 1) {
    if (tid < o) red[tid] = fmaxf(red[tid], red[tid + o]);
    __syncthreads();
  }
  m = red[0];
  __syncthreads();
  float s = 0.f;
  for (int n = beg + tid; n < end; n += 256) s += expf(gate[n] - m);
  red[tid] = s;
  __syncthreads();
  for (int o = 128; o > 0; o >>= 1) {
    if (tid < o) red[tid] += red[tid + o];
    __syncthreads();
  }
  float inv = (end > beg) ? (1.f / red[0]) : 0.f;

  const _Float16* Xp = X + f;
  float acc = 0.f;
  int n = beg;
  for (; n + 4 <= end; n += 4) {
    float a0 = expf(gate[n]     - m);
    float a1 = expf(gate[n + 1] - m);
    float a2 = expf(gate[n + 2] - m);
    float a3 = expf(gate[n + 3] - m);
    float x0 = (float)Xp[(size_t)(n)     * 1024];
    float x1 = (float)Xp[(size_t)(n + 1) * 1024];
    float x2 = (float)Xp[(size_t)(n + 2) * 1024];
    float x3 = (float)Xp[(size_t)(n + 3) * 1024];
    acc += a0 * x0 + a1 * x1 + a2 * x2 + a3 * x3;
  }
  for (; n < end; ++n) acc += expf(gate[n] - m) * (float)Xp[(size_t)n * 1024];

  const float inv_n = 1.f / NN;
  float mean = sums[f] * inv_n;
  float var  = sums[1024 + f] * inv_n - mean * mean;
  float sc   = g5[f] * rsqrtf(var + EPS_BN);
  float sh   = be5[f] - mean * sc;
  pooled[(size_t)g * 1024 + f] = (end > beg) ? (acc * inv * sc + sh) : 0.f;
}

// ------------------------------------------------------------------
// MLP head per graph from pooled row (LDS-staged, vectorized Wf2T reads).
// ------------------------------------------------------------------
__global__ __launch_bounds__(256) void k_head(
    const float* __restrict__ pooled,
    const float* __restrict__ Wf2T, const float* __restrict__ bf2,
    const float* __restrict__ Wf3, const float* __restrict__ bf3,
    const float* __restrict__ Wf4, const float* __restrict__ bf4,
    float* __restrict__ out)
{
  __shared__ float sp[1024];
  __shared__ float red[256];
  __shared__ float sp2[128];
  __shared__ float sp3[16];
  int g = blockIdx.x, tid = threadIdx.x;
  *(float4*)&sp[tid * 4] = *(const float4*)&pooled[(size_t)g * 1024 + tid * 4];
  __syncthreads();

  // Linear(1024 -> 128): 2 threads per output, contiguous float4 reads
  {
    int o = tid & 127, hf = tid >> 7;
    const float4* wrow = (const float4*)(Wf2T + (size_t)o * 1024 + hf * 512);
    const float* spp = &sp[hf * 512];
    float s2 = 0.f;
    #pragma unroll 4
    for (int k4 = 0; k4 < 128; ++k4) {
      float4 w = wrow[k4];
      s2 += w.x * spp[k4 * 4] + w.y * spp[k4 * 4 + 1]
          + w.z * spp[k4 * 4 + 2] + w.w * spp[k4 * 4 + 3];
    }
    red[tid] = s2;
  }
  __syncthreads();
  if (tid < 128) sp2[tid] = fmaxf(red[tid] + red[tid + 128] + bf2[tid], 0.f);
  __syncthreads();
  if (tid < 16) {
    float t = bf3[tid];
    for (int k = 0; k < 128; ++k) t += sp2[k] * Wf3[k * 16 + tid];
    sp3[tid] = fmaxf(t, 0.f);
  }
  __syncthreads();
  if (tid == 0) {
    float t = bf4[0];
    for (int k = 0; k < 16; ++k) t += sp3[k] * Wf4[k];
    out[g] = t;
  }
}

// ------------------------------------------------------------------
extern "C" void kernel_launch(void* const* d_in, const int* in_sizes, int n_in,
                              void* d_out, int out_size, void* d_ws, size_t ws_size,
                              hipStream_t stream) {
  const float* x     = (const float*)d_in[0];
  const int*   ei    = (const int*)d_in[1];
  const int*   batch = (const int*)d_in[2];
  const float* W[5]; const float* b[5]; const float* g[5]; const float* be[5];
  for (int l = 0; l < 5; ++l) {
    W[l]  = (const float*)d_in[3 + 4 * l];
    b[l]  = (const float*)d_in[4 + 4 * l];
    g[l]  = (const float*)d_in[5 + 4 * l];
    be[l] = (const float*)d_in[6 + 4 * l];
  }
  const float* Wg  = (const float*)d_in[23];
  const float* bg  = (const float*)d_in[24];
  const float* Wf2 = (const float*)d_in[25];
  const float* bf2 = (const float*)d_in[26];
  const float* Wf3 = (const float*)d_in[27];
  const float* bf3 = (const float*)d_in[28];
  const float* Wf4 = (const float*)d_in[29];
  const float* bf4 = (const float*)d_in[30];
  float* out = (float*)d_out;

  const int* row = ei;
  const int* col = ei + NE;

  char* base = (char*)d_ws;
  size_t off = 0;
  auto alloc = [&](size_t bytes) -> char* {
    char* p = base + off;
    off = (off + bytes + 255) & ~(size_t)255;
    return p;
  };
  // AH: r1(frag,K=1024) -> a4(frag,K=256)
  _Float16*  AH  = (_Float16*)alloc((size_t)MPAD * 1024 * 2);
  // AF: r2(frag,K=512) -> a5(frag,K=512)
  _Float16*  AF  = (_Float16*)alloc((size_t)MPAD * 512 * 2);
  _Float16*  ASM = (_Float16*)alloc((size_t)MPAD * 32 * 2);   // L1 A operand (frag)
  _Float16*  BF  = (_Float16*)alloc((size_t)NN * 512 * 2);    // G2(row) -> r3(row)
  _Float16*  BF2 = (_Float16*)alloc((size_t)NN * 512 * 2);    // G3(row) -> r4(row)
  _Float16*  H5  = (_Float16*)alloc((size_t)NN * 1024 * 2);   // r5(row)
  const int wtsz[5] = {1024 * 32, 512 * 1024, 256 * 512, 512 * 256, 1024 * 512};
  _Float16* WT[5];
  for (int l = 0; l < 5; ++l) WT[l] = (_Float16*)alloc((size_t)wtsz[l] * 2);
  float* c2  = (float*)alloc(512 * 4);
  float* c3  = (float*)alloc(256 * 4);
  float* dinv    = (float*)alloc(NN * 4);
  int*   indptr  = (int*)alloc((NN + 1) * 4);
  int*   cursor  = (int*)alloc(NN * 4);
  int2*  csw     = (int2*)alloc((size_t)NTOT * 8);
  int*   psum    = (int*)alloc((NBLK + 1) * 4);
  int*   pbase   = (int*)alloc((NBLK + 1) * 4);
  int*   goff    = (int*)alloc((NG + 1) * 4);
  float* gate    = (float*)alloc(NN * 4);
  float* wgf     = (float*)alloc(1024 * 4);
  float* cg      = (float*)alloc(4);
  float* pooled  = (float*)alloc((size_t)NG * 1024 * 4);
  float* Wf2T    = (float*)alloc((size_t)128 * 1024 * 4);
  size_t znf = 6656 + NN + NG + NN;
  float* zbase = (float*)alloc(znf * 4);
  float* bns  = zbase;
  int*   deg  = (int*)(zbase + 6656);
  int*   gcnt = (int*)(zbase + 6656 + NN);
  float* rsum = zbase + 6656 + NN + NG;
  float* bns1 = bns;          // F=1024
  float* bns2 = bns + 2048;   // F=512
  float* bns3 = bns + 3072;   // F=256
  float* bns4 = bns + 3584;   // F=512
  float* bns5 = bns + 4608;   // F=1024

  // ---- preprocessing ----
  hipMemsetAsync(zbase, 0, znf * 4, stream);
  k_deg<<<(NTOT + 255) / 256, 256, 0, stream>>>(col, deg, batch, gcnt);
  k_pre1<<<NBLK, 256, 0, stream>>>(deg, dinv, psum);
  k_pre2<<<1, 256, 0, stream>>>(psum, pbase, gcnt, goff);
  k_pre3<<<NBLK, 256, 0, stream>>>(deg, pbase, indptr, cursor);
  k_fill<<<(NTOT + 255) / 256, 256, 0, stream>>>(row, col, dinv, cursor, csw, rsum);
  k_wconv3<<<848, 256, 0, stream>>>(W[0], W[3], W[4], WT[0], WT[3], WT[4], Wf2, Wf2T);

  // ---- layer 1 (29 -> 1024): agg-first (frag); GEMM1 frag-out r1 + stats ----
  k_agg29<<<NN, 128, 0, stream>>>(x, indptr, csw, ASM);
  k_gemmf<32, 1><<<8 * 160, 256, 0, stream>>>(ASM, WT[0], b[0], nullptr, AH, bns1, 1024, 1, 8);

  // ---- layer 2 (1024 -> 512): BN1 folded into W2; transform-first ----
  k_wfold<<<512, 256, 0, stream>>>(W[1], 1024, 512, bns1, g[0], be[0], WT[1], c2);
  k_gemmf3<1024><<<4 * 160, 256, 0, stream>>>(AH, WT[1], nullptr, BF, nullptr, 512, 0, 4); // G2
  k_aggv2<0><<<2 * (NN / 8), 256, 0, stream>>>(BF, AF, nullptr, indptr, csw, rsum, c2, b[1], nullptr); // r2 frag
  k_statsf<512><<<256, 256, 0, stream>>>(AF, bns2);

  // ---- layer 3 (512 -> 256): BN2 folded into W3; transform-first ----
  k_wfold<<<256, 256, 0, stream>>>(W[2], 512, 256, bns2, g[1], be[1], WT[2], c3);
  k_gemmf3<512><<<2 * 160, 256, 0, stream>>>(AF, WT[2], nullptr, BF2, nullptr, 256, 0, 2); // G3
  k_aggp<0><<<NN / 8, 256, 0, stream>>>(BF2, nullptr, BF, indptr, csw, rsum, c3, b[2], nullptr); // r3 row
  k_stats16<<<512, 256, 0, stream>>>(BF, 256, bns3);

  // ---- layer 4 (256 -> 512): agg-first (frag), BN3 inline ----
  k_aggp<1><<<NN / 8, 256, 0, stream>>>(BF, AH, nullptr, indptr, csw, rsum, bns3, g[2], be[2]); // a4 frag
  k_gemmf3<256><<<4 * 160, 256, 0, stream>>>(AH, WT[3], b[3], BF2, bns4, 512, 1, 4); // r4 + stats

  // ---- layer 5 (512 -> 1024): agg-first (frag), BN4 inline ----
  k_aggv2<1><<<2 * (NN / 8), 256, 0, stream>>>(BF2, AF, nullptr, indptr, csw, rsum, bns4, g[3], be[3]); // a5 frag
  k_gemmf3<512><<<8 * 160, 256, 0, stream>>>(AF, WT[4], b[4], H5, bns5, 1024, 1, 8); // r5 + stats

  // ---- attention pooling (gate -> pool(fused softmax) -> head) ----
  k_gfold<<<1, 256, 0, stream>>>(bns5, g[4], be[4], Wg, bg, wgf, cg);
  k_gate3<<<NN / 4, 256, 0, stream>>>(H5, wgf, cg, gate);
  k_pool<<<NG * 4, 256, 0, stream>>>(H5, gate, goff, bns5, g[4], be[4], pooled);
  k_head<<<NG, 256, 0, stream>>>(pooled, Wf2T, bf2, Wf3, bf3, Wf4, bf4, out);
}